// Round 6
// baseline (140.449 us; speedup 1.0000x reference)
//
#include <hip/hip_runtime.h>

// Sin/cos position embedding: out[b, 2i] = sin(t[b] * N^(-2i/D)),
//                             out[b, 2i+1] = cos(t[b] * N^(-2i/D))
// 128 MiB written, 64 KiB read -> pure write-BW problem. Kernel-side time is
// ~25-30 us (dur_us also contains ~105 us of fixed harness poison/restore).
//
// Structure: each thread owns ONE float4 column (frequency pair, exp2 once),
// streams RPB rows of 16 B NON-TEMPORAL stores (bypass L2/LLC allocation for
// the pure write stream). t-values prefetched as wave-uniform SMEM batch.
// RPB=16 -> 2048 blocks -> 8 blocks/CU (full occupancy).

#define RPB 16

// Native clang vector type: __builtin_nontemporal_store requires it
// (HIP's float4 is a class and is rejected).
typedef float vfloat4 __attribute__((ext_vector_type(4)));

__global__ __launch_bounds__(256) void sinpos_kernel(
    const float* __restrict__ t,
    vfloat4* __restrict__ out,
    int q,                // D/4 = float4s per row
    float c)              // -2*log2(N_BASE)/D, so inv_freq = exp2(c*i)
{
    int j = blockIdx.x * blockDim.x + threadIdx.x;   // float4 column
    if (j >= q) return;
    int b0 = blockIdx.y * RPB;

    // Per-thread frequency pair: computed ONCE, reused for all rows.
    float i0 = (float)(2 * j);
    float f0 = __builtin_amdgcn_exp2f(c * i0);
    float f1 = __builtin_amdgcn_exp2f(c * (i0 + 1.0f));

    // Prefetch the tile's t values (wave-uniform, const offsets -> SMEM batch).
    const float inv2pi = 0.15915494309189535f;   // fold 1/2pi into t
    float ts[RPB];
#pragma unroll
    for (int r = 0; r < RPB; ++r) ts[r] = t[b0 + r] * inv2pi;

    vfloat4* p = out + (size_t)b0 * q + j;
#pragma unroll
    for (int r = 0; r < RPB; ++r) {
        // v_fract_f32: x - floor(x) in one instruction.
        float r0 = __builtin_amdgcn_fractf(ts[r] * f0);
        float r1 = __builtin_amdgcn_fractf(ts[r] * f1);
        vfloat4 v;
        v.x = __builtin_amdgcn_sinf(r0);
        v.y = __builtin_amdgcn_cosf(r0);
        v.z = __builtin_amdgcn_sinf(r1);
        v.w = __builtin_amdgcn_cosf(r1);
        __builtin_nontemporal_store(v, p);    // global_store_dwordx4 ... nt
        p += q;
    }
}

extern "C" void kernel_launch(void* const* d_in, const int* in_sizes, int n_in,
                              void* d_out, int out_size, void* d_ws, size_t ws_size,
                              hipStream_t stream) {
    const float* t = (const float*)d_in[0];

    int B = in_sizes[0];             // 16384
    int D = out_size / B;            // 2048
    int q = D / 4;                   // 512 float4s per row

    // c = -2*log2(10000)/D ; log2(10000) = 13.287712379549449
    float c = (float)(-2.0 * 13.287712379549449 / (double)D);

    dim3 block(256);
    dim3 grid((q + 255) / 256, B / RPB);   // B=16384 divisible by 16
    sinpos_kernel<<<grid, block, 0, stream>>>(t, (vfloat4*)d_out, q, c);
}